// Round 2
// baseline (188.785 us; speedup 1.0000x reference)
//
#include <hip/hip_runtime.h>
#include <math.h>

#define NG 4096
#define WI 80
#define HI 80
#define NPIX (WI*HI)
#define FOCAL 40.0f
#define LIM 1.3f

#define SH_C0 0.28209479177387814f
#define SH_C1 0.4886025119029199f

// ws layout (float slots of NG each):
// 0: depth | 1..10: gx,gy,ca,cb,cc,op,r,g,b,rcull (unsorted)
// 11: rank (int) | 12..21: sorted gx,gy,ca,cb,cc,op,r,g,b,rcull

__global__ __launch_bounds__(256) void prep_k(
    const float* __restrict__ means, const float* __restrict__ sh,
    const int* __restrict__ shidx, const int* __restrict__ gidx,
    const float* __restrict__ opac, const float* __restrict__ scales,
    const float* __restrict__ sfac, const float* __restrict__ rots,
    const float* __restrict__ ext, float* __restrict__ ws,
    float* __restrict__ radii_out)
{
  int i = blockIdx.x*blockDim.x + threadIdx.x;
  if (i >= NG) return;
  float e0=ext[0], e1=ext[1], e2=ext[2];
  float e4=ext[4], e5=ext[5], e6=ext[6];
  float e8=ext[8], e9=ext[9], e10=ext[10];
  float e12=ext[12], e13=ext[13], e14=ext[14];
  float m0=means[3*i+0], m1=means[3*i+1], m2=means[3*i+2];
  float tx = m0*e0 + m1*e4 + m2*e8  + e12;
  float ty = m0*e1 + m1*e5 + m2*e9  + e13;
  float tz = m0*e2 + m1*e6 + m2*e10 + e14;
  bool infront = tz > 0.2f;
  float tzs = infront ? tz : 1.0f;
  float inv_tzs = 1.0f / tzs;
  float gx = ((tx*inv_tzs + 1.0f)*WI - 1.0f)*0.5f;
  float gy = ((ty*inv_tzs + 1.0f)*HI - 1.0f)*0.5f;

  int gi = gidx[i];
  float sf = sfac[i];
  float s0 = scales[3*gi+0]*sf, s1 = scales[3*gi+1]*sf, s2 = scales[3*gi+2]*sf;
  float qw = rots[4*gi+0], qx = rots[4*gi+1], qy = rots[4*gi+2], qz = rots[4*gi+3];
  float qinv = rsqrtf(qw*qw+qx*qx+qy*qy+qz*qz);
  qw*=qinv; qx*=qinv; qy*=qinv; qz*=qinv;
  float r00 = 1.0f - 2.0f*(qy*qy+qz*qz);
  float r01 = 2.0f*(qx*qy - qw*qz);
  float r02 = 2.0f*(qx*qz + qw*qy);
  float r10 = 2.0f*(qx*qy + qw*qz);
  float r11 = 1.0f - 2.0f*(qx*qx+qz*qz);
  float r12 = 2.0f*(qy*qz - qw*qx);
  float r20 = 2.0f*(qx*qz - qw*qy);
  float r21 = 2.0f*(qy*qz + qw*qx);
  float r22 = 1.0f - 2.0f*(qx*qx+qy*qy);
  float v0 = s0*s0, v1 = s1*s1, v2 = s2*s2;
  float C00 = r00*r00*v0 + r01*r01*v1 + r02*r02*v2;
  float C01 = r00*r10*v0 + r01*r11*v1 + r02*r12*v2;
  float C02 = r00*r20*v0 + r01*r21*v1 + r02*r22*v2;
  float C11 = r10*r10*v0 + r11*r11*v1 + r12*r12*v2;
  float C12 = r10*r20*v0 + r11*r21*v1 + r12*r22*v2;
  float C22 = r20*r20*v0 + r21*r21*v1 + r22*r22*v2;
  float W0x=e0, W0y=e4, W0z=e8;
  float W1x=e1, W1y=e5, W1z=e9;
  float W2x=e2, W2y=e6, W2z=e10;
  float B00 = W0x*C00 + W0y*C01 + W0z*C02;
  float B01 = W0x*C01 + W0y*C11 + W0z*C12;
  float B02 = W0x*C02 + W0y*C12 + W0z*C22;
  float B10 = W1x*C00 + W1y*C01 + W1z*C02;
  float B11 = W1x*C01 + W1y*C11 + W1z*C12;
  float B12 = W1x*C02 + W1y*C12 + W1z*C22;
  float B20 = W2x*C00 + W2y*C01 + W2z*C02;
  float B21 = W2x*C01 + W2y*C11 + W2z*C12;
  float B22 = W2x*C02 + W2y*C12 + W2z*C22;
  float V00 = B00*W0x + B01*W0y + B02*W0z;
  float V01 = B00*W1x + B01*W1y + B02*W1z;
  float V02 = B00*W2x + B01*W2y + B02*W2z;
  float V11 = B10*W1x + B11*W1y + B12*W1z;
  float V12 = B10*W2x + B11*W2y + B12*W2z;
  float V22 = B20*W2x + B21*W2y + B22*W2z;
  float txz = tx*inv_tzs, tyz = ty*inv_tzs;
  float txc = fminf(fmaxf(txz, -LIM), LIM) * tzs;
  float tyc = fminf(fmaxf(tyz, -LIM), LIM) * tzs;
  float jx  = FOCAL*inv_tzs;
  float jy  = FOCAL*inv_tzs;
  float jz0 = -FOCAL*txc*inv_tzs*inv_tzs;
  float jz1 = -FOCAL*tyc*inv_tzs*inv_tzs;
  float c00 = jx*jx*V00 + 2.0f*jx*jz0*V02 + jz0*jz0*V22;
  float c01 = jx*jy*V01 + jx*jz1*V02 + jz0*jy*V12 + jz0*jz1*V22;
  float c11 = jy*jy*V11 + 2.0f*jy*jz1*V12 + jz1*jz1*V22;
  float a = c00 + 0.3f;
  float b = c01;
  float c = c11 + 0.3f;
  float det = a*c - b*b;
  bool valid = infront && (det > 0.0f);
  float dets = (det != 0.0f) ? det : 1.0f;
  float ca = c/dets, cb = -b/dets, cc = a/dets;
  float mid = 0.5f*(a+c);
  float lam1 = mid + sqrtf(fmaxf(0.1f, mid*mid - det));
  float radf = valid ? ceilf(3.0f*sqrtf(lam1)) : 0.0f;
  float cp0 = -(e12*e0 + e13*e1 + e14*e2);
  float cp1 = -(e12*e4 + e13*e5 + e14*e6);
  float cp2 = -(e12*e8 + e13*e9 + e14*e10);
  float dx0 = m0-cp0, dy0 = m1-cp1, dz0 = m2-cp2;
  float dn = rsqrtf(dx0*dx0+dy0*dy0+dz0*dz0);
  float x = dx0*dn, y = dy0*dn, z = dz0*dn;
  float xx=x*x, yy=y*y, zz=z*z;
  float xy=x*y, yz=y*z, xz=x*z;
  float bf[16];
  bf[0]  = SH_C0;
  bf[1]  = -SH_C1*y;
  bf[2]  =  SH_C1*z;
  bf[3]  = -SH_C1*x;
  bf[4]  =  1.0925484305920792f*xy;
  bf[5]  = -1.0925484305920792f*yz;
  bf[6]  =  0.31539156525252005f*(2.0f*zz-xx-yy);
  bf[7]  = -1.0925484305920792f*xz;
  bf[8]  =  0.5462742152960396f*(xx-yy);
  bf[9]  = -0.5900435899266435f*y*(3.0f*xx-yy);
  bf[10] =  2.890611442640554f*xy*z;
  bf[11] = -0.4570457994644658f*y*(4.0f*zz-xx-yy);
  bf[12] =  0.3731763325901154f*z*(2.0f*zz-3.0f*xx-3.0f*yy);
  bf[13] = -0.4570457994644658f*x*(4.0f*zz-xx-yy);
  bf[14] =  1.445305721320277f*z*(xx-yy);
  bf[15] = -0.5900435899266435f*x*(xx-yy-3.0f*zz);
  const float* S = sh + (long)shidx[i]*48;
  float cr=0.f, cg=0.f, cbl=0.f;
  #pragma unroll
  for (int j=0;j<16;j++) {
    float w = bf[j];
    cr  += w*S[j*3+0];
    cg  += w*S[j*3+1];
    cbl += w*S[j*3+2];
  }
  cr  = fmaxf(cr +0.5f, 0.0f);
  cg  = fmaxf(cg +0.5f, 0.0f);
  cbl = fmaxf(cbl+0.5f, 0.0f);

  float op = valid ? opac[i] : 0.0f;
  float depth = valid ? tz : __builtin_inff();
  // Exact cull radius: alpha >= 1/255 requires |d|^2 <= 2*ln(255*op)*lam1
  // (power <= -|d|^2/(2*lam1) since lam1 >= lambda_max). Reference zeroes
  // alpha < 1/255 itself, so culling beyond rc is exact, not approximate.
  float rc = valid ? sqrtf(fmaxf(0.0f, 2.0f*logf(255.0f*op))*lam1) + 0.01f : 0.0f;
  ws[0*NG+i]=depth;
  ws[1*NG+i]=gx;  ws[2*NG+i]=gy;
  ws[3*NG+i]=ca;  ws[4*NG+i]=cb;  ws[5*NG+i]=cc;
  ws[6*NG+i]=op;
  ws[7*NG+i]=cr;  ws[8*NG+i]=cg;  ws[9*NG+i]=cbl;
  ws[10*NG+i]=rc;
  ((int*)ws)[11*NG+i] = 0;          // zero rank for atomic accumulation
  radii_out[i] = radf;              // int32 reference values, written as floats
}

// O(N^2) stable rank: rank[i] = #{j : d_j < d_i || (d_j == d_i && j < i)}
__global__ __launch_bounds__(256) void rank_k(const float* __restrict__ ws, int* __restrict__ rank)
{
  __shared__ float dj[256];
  int i = blockIdx.x*256 + threadIdx.x;
  int jbase = blockIdx.y*256;
  float di = ws[i];
  dj[threadIdx.x] = ws[jbase + threadIdx.x];
  __syncthreads();
  int cnt = 0;
  #pragma unroll 8
  for (int j=0;j<256;j++) {
    float d = dj[j];
    cnt += (d < di) || (d == di && (jbase+j) < i);
  }
  atomicAdd(&rank[i], cnt);
}

__global__ __launch_bounds__(256) void scatter_k(const float* __restrict__ ws,
                                                 const int* __restrict__ rank,
                                                 float* __restrict__ sorted)
{
  int i = blockIdx.x*256 + threadIdx.x;
  int r = rank[i];
  #pragma unroll
  for (int a=0;a<10;a++)
    sorted[a*NG + r] = ws[(1+a)*NG + i];
}

// One wave per 8x8 tile. Stream sorted gaussians in 64-chunks, ballot-compact
// tile hits (order preserved => depth order preserved), gather params to LDS,
// per-pixel sequential front-to-back blend with private T. No cross-lane scan.
__global__ __launch_bounds__(64) void composite_k(const float* __restrict__ sg,
                                                  const float* __restrict__ bg,
                                                  float* __restrict__ out)
{
  __shared__ int   qidx[64];
  __shared__ float st[9][64];
  int lane = threadIdx.x;
  int tile = blockIdx.x;
  int x0 = (tile % 10) * 8, y0 = (tile / 10) * 8;
  float px = (float)(x0 + (lane & 7));
  float py = (float)(y0 + (lane >> 3));
  float bx0 = (float)x0,      by0 = (float)y0;
  float bx1 = (float)(x0+7),  by1 = (float)(y0+7);
  float T = 1.0f, accr=0.f, accg=0.f, accb=0.f;

  for (int chunk = 0; chunk < NG/64; ++chunk) {
    int g = chunk*64 + lane;
    float gxv = sg[0*NG+g];
    float gyv = sg[1*NG+g];
    float rc  = sg[9*NG+g];
    bool hit = (rc > 0.0f) &&
               (gxv >= bx0-rc) && (gxv <= bx1+rc) &&
               (gyv >= by0-rc) && (gyv <= by1+rc);
    unsigned long long m = __ballot(hit);
    if (m) {
      int pos = __popcll(m & ((1ull<<lane)-1ull));
      if (hit) qidx[pos] = g;
      int qn = __popcll(m);
      __syncthreads();
      if (lane < qn) {
        int gi = qidx[lane];
        #pragma unroll
        for (int a=0;a<9;a++) st[a][lane] = sg[a*NG+gi];
      }
      __syncthreads();
      for (int e=0;e<qn;e++) {
        float dx = st[0][e]-px, dy = st[1][e]-py;
        float ca = st[2][e], cb = st[3][e], cc = st[4][e], op = st[5][e];
        float power = -0.5f*(ca*dx*dx + cc*dy*dy) - cb*dx*dy;
        float al = 0.0f;
        if (power <= 0.0f) {
          float av = fminf(0.99f, op*__expf(power));
          if (av >= (1.0f/255.0f)) al = av;
        }
        float w = al*T;
        accr += w*st[6][e];
        accg += w*st[7][e];
        accb += w*st[8][e];
        T *= 1.0f - al;
      }
      if (__ballot(T >= 1e-4f) == 0ull) break;  // exact: ref zeroes w once T<1e-4
      __syncthreads();
    }
  }
  int p = (y0 + (lane>>3))*WI + (x0 + (lane&7));
  out[0*NPIX+p] = accr + T*bg[0];
  out[1*NPIX+p] = accg + T*bg[1];
  out[2*NPIX+p] = accb + T*bg[2];
}

extern "C" void kernel_launch(void* const* d_in, const int* in_sizes, int n_in,
                              void* d_out, int out_size, void* d_ws, size_t ws_size,
                              hipStream_t stream) {
  const float* means  = (const float*)d_in[0];
  const float* sh     = (const float*)d_in[1];
  const int*   shidx  = (const int*)  d_in[2];
  const int*   gidx   = (const int*)  d_in[3];
  const float* opac   = (const float*)d_in[4];
  const float* scales = (const float*)d_in[5];
  const float* sfac   = (const float*)d_in[6];
  const float* rots   = (const float*)d_in[7];
  const float* ext    = (const float*)d_in[8];
  const float* bg     = (const float*)d_in[9];
  float* out = (float*)d_out;
  float* ws  = (float*)d_ws;

  prep_k<<<NG/256, 256, 0, stream>>>(means, sh, shidx, gidx, opac, scales, sfac,
                                     rots, ext, ws, out + 3*NPIX);
  dim3 rg(NG/256, NG/256);
  rank_k<<<rg, 256, 0, stream>>>(ws, (int*)(ws + 11*NG));
  scatter_k<<<NG/256, 256, 0, stream>>>(ws, (const int*)(ws + 11*NG), ws + 12*NG);
  composite_k<<<100, 64, 0, stream>>>(ws + 12*NG, bg, out);
}

// Round 3
// 110.565 us; speedup vs baseline: 1.7075x; 1.7075x over previous
//
#include <hip/hip_runtime.h>
#include <math.h>

#define NG 4096
#define WI 80
#define HI 80
#define NPIX (WI*HI)
#define FOCAL 40.0f
#define LIM 1.3f
#define CAP 1024

#define SH_C0 0.28209479177387814f
#define SH_C1 0.4886025119029199f

// One block per 8x8 tile, 512 threads (8 waves).
// Phase A: each block preps ALL 4096 gaussians (8 chunks x 512) in registers,
//          hit-tests vs its tile (exact alpha>=1/255 cull), compacts hits to LDS
//          with key = depth_bits<<22 | gauss_idx<<10 | slot.
// Phase B: bitonic sort keys (depth asc, stable by idx — matches jnp.argsort).
// Phase C: 8-way segment-split front-to-back blend (compositing monoid),
//          per-wave early-out on own partial T (exact under ref's 1e-4 cutoff),
//          combine 8 partials front-to-back. Block 0 also writes radii.

__global__ __launch_bounds__(512) void tile_k(
    const float* __restrict__ means, const float* __restrict__ sh,
    const int* __restrict__ shidx, const int* __restrict__ gidx,
    const float* __restrict__ opac, const float* __restrict__ scales,
    const float* __restrict__ sfac, const float* __restrict__ rots,
    const float* __restrict__ ext, const float* __restrict__ bg,
    float* __restrict__ out)
{
  __shared__ unsigned long long kds[CAP];
  __shared__ float pr[CAP][9];
  __shared__ float pT[8][64], pR[8][64], pG[8][64], pB[8][64];
  __shared__ int scnt;
  int tid = threadIdx.x;
  if (tid == 0) scnt = 0;
  __syncthreads();

  int tile = blockIdx.x;
  int x0 = (tile % 10) * 8, y0 = (tile / 10) * 8;
  float bx0 = (float)x0, bx1 = (float)(x0 + 7);
  float by0 = (float)y0, by1 = (float)(y0 + 7);

  float e0=ext[0],  e1=ext[1],  e2=ext[2];
  float e4=ext[4],  e5=ext[5],  e6=ext[6];
  float e8=ext[8],  e9=ext[9],  e10=ext[10];
  float e12=ext[12], e13=ext[13], e14=ext[14];
  float cp0 = -(e12*e0 + e13*e1 + e14*e2);
  float cp1 = -(e12*e4 + e13*e5 + e14*e6);
  float cp2 = -(e12*e8 + e13*e9 + e14*e10);

  for (int c = 0; c < NG/512; ++c) {
    int g = c*512 + tid;
    float m0 = means[3*g+0], m1 = means[3*g+1], m2 = means[3*g+2];
    float tx = m0*e0 + m1*e4 + m2*e8  + e12;
    float ty = m0*e1 + m1*e5 + m2*e9  + e13;
    float tz = m0*e2 + m1*e6 + m2*e10 + e14;
    bool infront = tz > 0.2f;
    float tzs = infront ? tz : 1.0f;
    float inv_tzs = 1.0f / tzs;
    float gx = ((tx*inv_tzs + 1.0f)*WI - 1.0f)*0.5f;
    float gy = ((ty*inv_tzs + 1.0f)*HI - 1.0f)*0.5f;

    int gi = gidx[g];
    float sf = sfac[g];
    float s0 = scales[3*gi+0]*sf, s1 = scales[3*gi+1]*sf, s2 = scales[3*gi+2]*sf;
    float qw = rots[4*gi+0], qx = rots[4*gi+1], qy = rots[4*gi+2], qz = rots[4*gi+3];
    float qinv = rsqrtf(qw*qw+qx*qx+qy*qy+qz*qz);
    qw*=qinv; qx*=qinv; qy*=qinv; qz*=qinv;
    float r00 = 1.0f - 2.0f*(qy*qy+qz*qz);
    float r01 = 2.0f*(qx*qy - qw*qz);
    float r02 = 2.0f*(qx*qz + qw*qy);
    float r10 = 2.0f*(qx*qy + qw*qz);
    float r11 = 1.0f - 2.0f*(qx*qx+qz*qz);
    float r12 = 2.0f*(qy*qz - qw*qx);
    float r20 = 2.0f*(qx*qz - qw*qy);
    float r21 = 2.0f*(qy*qz + qw*qx);
    float r22 = 1.0f - 2.0f*(qx*qx+qy*qy);
    float v0 = s0*s0, v1 = s1*s1, v2 = s2*s2;
    float C00 = r00*r00*v0 + r01*r01*v1 + r02*r02*v2;
    float C01 = r00*r10*v0 + r01*r11*v1 + r02*r12*v2;
    float C02 = r00*r20*v0 + r01*r21*v1 + r02*r22*v2;
    float C11 = r10*r10*v0 + r11*r11*v1 + r12*r12*v2;
    float C12 = r10*r20*v0 + r11*r21*v1 + r12*r22*v2;
    float C22 = r20*r20*v0 + r21*r21*v1 + r22*r22*v2;
    float W0x=e0, W0y=e4, W0z=e8;
    float W1x=e1, W1y=e5, W1z=e9;
    float W2x=e2, W2y=e6, W2z=e10;
    float B00 = W0x*C00 + W0y*C01 + W0z*C02;
    float B01 = W0x*C01 + W0y*C11 + W0z*C12;
    float B02 = W0x*C02 + W0y*C12 + W0z*C22;
    float B10 = W1x*C00 + W1y*C01 + W1z*C02;
    float B11 = W1x*C01 + W1y*C11 + W1z*C12;
    float B12 = W1x*C02 + W1y*C12 + W1z*C22;
    float B20 = W2x*C00 + W2y*C01 + W2z*C02;
    float B21 = W2x*C01 + W2y*C11 + W2z*C12;
    float B22 = W2x*C02 + W2y*C12 + W2z*C22;
    float V00 = B00*W0x + B01*W0y + B02*W0z;
    float V01 = B00*W1x + B01*W1y + B02*W1z;
    float V02 = B00*W2x + B01*W2y + B02*W2z;
    float V11 = B10*W1x + B11*W1y + B12*W1z;
    float V12 = B10*W2x + B11*W2y + B12*W2z;
    float V22 = B20*W2x + B21*W2y + B22*W2z;
    float txz = tx*inv_tzs, tyz = ty*inv_tzs;
    float txc = fminf(fmaxf(txz, -LIM), LIM) * tzs;
    float tyc = fminf(fmaxf(tyz, -LIM), LIM) * tzs;
    float jx  = FOCAL*inv_tzs;
    float jy  = FOCAL*inv_tzs;
    float jz0 = -FOCAL*txc*inv_tzs*inv_tzs;
    float jz1 = -FOCAL*tyc*inv_tzs*inv_tzs;
    float c00 = jx*jx*V00 + 2.0f*jx*jz0*V02 + jz0*jz0*V22;
    float c01 = jx*jy*V01 + jx*jz1*V02 + jz0*jy*V12 + jz0*jz1*V22;
    float c11 = jy*jy*V11 + 2.0f*jy*jz1*V12 + jz1*jz1*V22;
    float a = c00 + 0.3f;
    float b = c01;
    float cf = c11 + 0.3f;
    float det = a*cf - b*b;
    bool valid = infront && (det > 0.0f);
    float dets = (det != 0.0f) ? det : 1.0f;
    float ca = cf/dets, cb = -b/dets, cc = a/dets;
    float mid = 0.5f*(a+cf);
    float lam1 = mid + sqrtf(fmaxf(0.1f, mid*mid - det));
    float radf = valid ? ceilf(3.0f*sqrtf(lam1)) : 0.0f;
    if (blockIdx.x == 0) out[3*NPIX + g] = radf;   // radii (int32 vals as float)

    float op = valid ? opac[g] : 0.0f;
    // exact cull radius: alpha>=1/255 needs |d|^2 <= 2 ln(255 op) lam1
    float rc = valid ? sqrtf(fmaxf(0.0f, 2.0f*logf(255.0f*op))*lam1) + 0.01f : 0.0f;
    // circle-vs-box
    float nx = fminf(fmaxf(gx, bx0), bx1) - gx;
    float ny = fminf(fmaxf(gy, by0), by1) - gy;
    bool hit = (rc > 0.0f) && (nx*nx + ny*ny <= rc*rc);
    if (hit) {
      int slot = atomicAdd(&scnt, 1);
      if (slot < CAP) {
        // SH color (hit lanes only)
        float dx0 = m0-cp0, dy0 = m1-cp1, dz0 = m2-cp2;
        float dn = rsqrtf(dx0*dx0+dy0*dy0+dz0*dz0);
        float x = dx0*dn, y = dy0*dn, z = dz0*dn;
        float xx=x*x, yy=y*y, zz=z*z;
        float xy=x*y, yz=y*z, xz=x*z;
        float bf[16];
        bf[0]  = SH_C0;
        bf[1]  = -SH_C1*y;
        bf[2]  =  SH_C1*z;
        bf[3]  = -SH_C1*x;
        bf[4]  =  1.0925484305920792f*xy;
        bf[5]  = -1.0925484305920792f*yz;
        bf[6]  =  0.31539156525252005f*(2.0f*zz-xx-yy);
        bf[7]  = -1.0925484305920792f*xz;
        bf[8]  =  0.5462742152960396f*(xx-yy);
        bf[9]  = -0.5900435899266435f*y*(3.0f*xx-yy);
        bf[10] =  2.890611442640554f*xy*z;
        bf[11] = -0.4570457994644658f*y*(4.0f*zz-xx-yy);
        bf[12] =  0.3731763325901154f*z*(2.0f*zz-3.0f*xx-3.0f*yy);
        bf[13] = -0.4570457994644658f*x*(4.0f*zz-xx-yy);
        bf[14] =  1.445305721320277f*z*(xx-yy);
        bf[15] = -0.5900435899266435f*x*(xx-yy-3.0f*zz);
        const float* S = sh + (long)shidx[g]*48;
        float cr=0.f, cg=0.f, cbl=0.f;
        #pragma unroll
        for (int j=0;j<16;j++) {
          float w = bf[j];
          cr  += w*S[j*3+0];
          cg  += w*S[j*3+1];
          cbl += w*S[j*3+2];
        }
        cr  = fmaxf(cr +0.5f, 0.0f);
        cg  = fmaxf(cg +0.5f, 0.0f);
        cbl = fmaxf(cbl+0.5f, 0.0f);

        kds[slot] = ((unsigned long long)__float_as_uint(tz) << 22)
                  | ((unsigned long long)g << 10)
                  | (unsigned long long)slot;
        pr[slot][0]=gx; pr[slot][1]=gy;
        pr[slot][2]=ca; pr[slot][3]=cb; pr[slot][4]=cc;
        pr[slot][5]=op; pr[slot][6]=cr; pr[slot][7]=cg; pr[slot][8]=cbl;
      }
    }
  }
  __syncthreads();
  int cnt = scnt; if (cnt > CAP) cnt = CAP;

  // bitonic sort (ascending), pad to pow2
  int n = 1; while (n < cnt) n <<= 1;
  for (int i = tid; i < n; i += 512) if (i >= cnt) kds[i] = ~0ull;
  __syncthreads();
  for (int k = 2; k <= n; k <<= 1) {
    for (int j = k >> 1; j > 0; j >>= 1) {
      for (int i = tid; i < n; i += 512) {
        int l = i ^ j;
        if (l > i) {
          unsigned long long va = kds[i], vb = kds[l];
          bool asc = ((i & k) == 0);
          if ((va > vb) == asc) { kds[i] = vb; kds[l] = va; }
        }
      }
      __syncthreads();
    }
  }

  // 8-way segment-split blend
  int wv = tid >> 6, lane = tid & 63;
  float px = (float)(x0 + (lane & 7));
  float py = (float)(y0 + (lane >> 3));
  int seg = (cnt + 7) >> 3;
  int s0i = wv*seg;
  int s1i = s0i + seg; if (s1i > cnt) s1i = cnt;
  float T = 1.0f, ar = 0.f, ag = 0.f, ab = 0.f;
  for (int e = s0i; e < s1i; ++e) {
    int slot = (int)(kds[e] & 1023ull);
    const float* q = pr[slot];
    float dx = q[0]-px, dy = q[1]-py;
    float power = -0.5f*(q[2]*dx*dx + q[4]*dy*dy) - q[3]*dx*dy;
    float al = 0.0f;
    if (power <= 0.0f) {
      float av = fminf(0.99f, q[5]*__expf(power));
      if (av >= (1.0f/255.0f)) al = av;
    }
    float w = al*T;
    ar += w*q[6]; ag += w*q[7]; ab += w*q[8];
    T *= 1.0f - al;
    if (__ballot(T >= 1e-4f) == 0ull) break;  // own-partial cutoff (exact)
  }
  pT[wv][lane]=T; pR[wv][lane]=ar; pG[wv][lane]=ag; pB[wv][lane]=ab;
  __syncthreads();

  if (tid < 64) {
    float Tg = 1.0f, r = 0.f, g2 = 0.f, b2 = 0.f;
    #pragma unroll
    for (int w = 0; w < 8; ++w) {
      r  += Tg*pR[w][tid];
      g2 += Tg*pG[w][tid];
      b2 += Tg*pB[w][tid];
      Tg *= pT[w][tid];
    }
    int p = (y0 + (tid>>3))*WI + (x0 + (tid&7));
    out[0*NPIX+p] = r  + Tg*bg[0];
    out[1*NPIX+p] = g2 + Tg*bg[1];
    out[2*NPIX+p] = b2 + Tg*bg[2];
  }
}

extern "C" void kernel_launch(void* const* d_in, const int* in_sizes, int n_in,
                              void* d_out, int out_size, void* d_ws, size_t ws_size,
                              hipStream_t stream) {
  const float* means  = (const float*)d_in[0];
  const float* sh     = (const float*)d_in[1];
  const int*   shidx  = (const int*)  d_in[2];
  const int*   gidx   = (const int*)  d_in[3];
  const float* opac   = (const float*)d_in[4];
  const float* scales = (const float*)d_in[5];
  const float* sfac   = (const float*)d_in[6];
  const float* rots   = (const float*)d_in[7];
  const float* ext    = (const float*)d_in[8];
  const float* bg     = (const float*)d_in[9];
  float* out = (float*)d_out;

  tile_k<<<100, 512, 0, stream>>>(means, sh, shidx, gidx, opac, scales, sfac,
                                  rots, ext, bg, out);
}

// Round 4
// 97.646 us; speedup vs baseline: 1.9334x; 1.1323x over previous
//
#include <hip/hip_runtime.h>
#include <math.h>

#define NG 4096
#define WI 80
#define HI 80
#define NPIX (WI*HI)
#define FOCAL 40.0f
#define LIM 1.3f
#define CAP 1024

#define SH_C0 0.28209479177387814f
#define SH_C1 0.4886025119029199f

// prep_k: per-gaussian params computed ONCE.
// ws layout: float4 c4[NG] {gx,gy,rc,depth} | float4 a4[NG] {ca,cb,cc,op} | float4 col4[NG] {r,g,b,0}
__global__ __launch_bounds__(256) void prep_k(
    const float* __restrict__ means, const float* __restrict__ sh,
    const int* __restrict__ shidx, const int* __restrict__ gidx,
    const float* __restrict__ opac, const float* __restrict__ scales,
    const float* __restrict__ sfac, const float* __restrict__ rots,
    const float* __restrict__ ext, float4* __restrict__ ws,
    float* __restrict__ radii_out)
{
  int i = blockIdx.x*blockDim.x + threadIdx.x;
  if (i >= NG) return;
  float e0=ext[0],  e1=ext[1],  e2=ext[2];
  float e4=ext[4],  e5=ext[5],  e6=ext[6];
  float e8=ext[8],  e9=ext[9],  e10=ext[10];
  float e12=ext[12], e13=ext[13], e14=ext[14];
  float m0=means[3*i+0], m1=means[3*i+1], m2=means[3*i+2];
  float tx = m0*e0 + m1*e4 + m2*e8  + e12;
  float ty = m0*e1 + m1*e5 + m2*e9  + e13;
  float tz = m0*e2 + m1*e6 + m2*e10 + e14;
  bool infront = tz > 0.2f;
  float tzs = infront ? tz : 1.0f;
  float inv_tzs = 1.0f / tzs;
  float gx = ((tx*inv_tzs + 1.0f)*WI - 1.0f)*0.5f;
  float gy = ((ty*inv_tzs + 1.0f)*HI - 1.0f)*0.5f;

  int gi = gidx[i];
  float sf = sfac[i];
  float s0 = scales[3*gi+0]*sf, s1 = scales[3*gi+1]*sf, s2 = scales[3*gi+2]*sf;
  float qw = rots[4*gi+0], qx = rots[4*gi+1], qy = rots[4*gi+2], qz = rots[4*gi+3];
  float qinv = rsqrtf(qw*qw+qx*qx+qy*qy+qz*qz);
  qw*=qinv; qx*=qinv; qy*=qinv; qz*=qinv;
  float r00 = 1.0f - 2.0f*(qy*qy+qz*qz);
  float r01 = 2.0f*(qx*qy - qw*qz);
  float r02 = 2.0f*(qx*qz + qw*qy);
  float r10 = 2.0f*(qx*qy + qw*qz);
  float r11 = 1.0f - 2.0f*(qx*qx+qz*qz);
  float r12 = 2.0f*(qy*qz - qw*qx);
  float r20 = 2.0f*(qx*qz - qw*qy);
  float r21 = 2.0f*(qy*qz + qw*qx);
  float r22 = 1.0f - 2.0f*(qx*qx+qy*qy);
  float v0 = s0*s0, v1 = s1*s1, v2 = s2*s2;
  float C00 = r00*r00*v0 + r01*r01*v1 + r02*r02*v2;
  float C01 = r00*r10*v0 + r01*r11*v1 + r02*r12*v2;
  float C02 = r00*r20*v0 + r01*r21*v1 + r02*r22*v2;
  float C11 = r10*r10*v0 + r11*r11*v1 + r12*r12*v2;
  float C12 = r10*r20*v0 + r11*r21*v1 + r12*r22*v2;
  float C22 = r20*r20*v0 + r21*r21*v1 + r22*r22*v2;
  float W0x=e0, W0y=e4, W0z=e8;
  float W1x=e1, W1y=e5, W1z=e9;
  float W2x=e2, W2y=e6, W2z=e10;
  float B00 = W0x*C00 + W0y*C01 + W0z*C02;
  float B01 = W0x*C01 + W0y*C11 + W0z*C12;
  float B02 = W0x*C02 + W0y*C12 + W0z*C22;
  float B10 = W1x*C00 + W1y*C01 + W1z*C02;
  float B11 = W1x*C01 + W1y*C11 + W1z*C12;
  float B12 = W1x*C02 + W1y*C12 + W1z*C22;
  float B20 = W2x*C00 + W2y*C01 + W2z*C02;
  float B21 = W2x*C01 + W2y*C11 + W2z*C12;
  float B22 = W2x*C02 + W2y*C12 + W2z*C22;
  float V00 = B00*W0x + B01*W0y + B02*W0z;
  float V01 = B00*W1x + B01*W1y + B02*W1z;
  float V02 = B00*W2x + B01*W2y + B02*W2z;
  float V11 = B10*W1x + B11*W1y + B12*W1z;
  float V12 = B10*W2x + B11*W2y + B12*W2z;
  float V22 = B20*W2x + B21*W2y + B22*W2z;
  float txz = tx*inv_tzs, tyz = ty*inv_tzs;
  float txc = fminf(fmaxf(txz, -LIM), LIM) * tzs;
  float tyc = fminf(fmaxf(tyz, -LIM), LIM) * tzs;
  float jx  = FOCAL*inv_tzs;
  float jy  = FOCAL*inv_tzs;
  float jz0 = -FOCAL*txc*inv_tzs*inv_tzs;
  float jz1 = -FOCAL*tyc*inv_tzs*inv_tzs;
  float c00 = jx*jx*V00 + 2.0f*jx*jz0*V02 + jz0*jz0*V22;
  float c01 = jx*jy*V01 + jx*jz1*V02 + jz0*jy*V12 + jz0*jz1*V22;
  float c11 = jy*jy*V11 + 2.0f*jy*jz1*V12 + jz1*jz1*V22;
  float a = c00 + 0.3f;
  float b = c01;
  float cf = c11 + 0.3f;
  float det = a*cf - b*b;
  bool valid = infront && (det > 0.0f);
  float dets = (det != 0.0f) ? det : 1.0f;
  float ca = cf/dets, cb = -b/dets, cc = a/dets;
  float mid = 0.5f*(a+cf);
  float lam1 = mid + sqrtf(fmaxf(0.1f, mid*mid - det));
  float radf = valid ? ceilf(3.0f*sqrtf(lam1)) : 0.0f;
  radii_out[i] = radf;

  float op = valid ? opac[i] : 0.0f;
  // exact cull: alpha >= 1/255 requires |d|^2 <= 2 ln(255 op) lam1 (lam1 >= lambda_max)
  float rc = valid ? sqrtf(fmaxf(0.0f, 2.0f*logf(255.0f*op))*lam1) + 0.01f : 0.0f;

  float cp0 = -(e12*e0 + e13*e1 + e14*e2);
  float cp1 = -(e12*e4 + e13*e5 + e14*e6);
  float cp2 = -(e12*e8 + e13*e9 + e14*e10);
  float dx0 = m0-cp0, dy0 = m1-cp1, dz0 = m2-cp2;
  float dn = rsqrtf(dx0*dx0+dy0*dy0+dz0*dz0);
  float x = dx0*dn, y = dy0*dn, z = dz0*dn;
  float xx=x*x, yy=y*y, zz=z*z;
  float xy=x*y, yz=y*z, xz=x*z;
  float bf[16];
  bf[0]  = SH_C0;
  bf[1]  = -SH_C1*y;
  bf[2]  =  SH_C1*z;
  bf[3]  = -SH_C1*x;
  bf[4]  =  1.0925484305920792f*xy;
  bf[5]  = -1.0925484305920792f*yz;
  bf[6]  =  0.31539156525252005f*(2.0f*zz-xx-yy);
  bf[7]  = -1.0925484305920792f*xz;
  bf[8]  =  0.5462742152960396f*(xx-yy);
  bf[9]  = -0.5900435899266435f*y*(3.0f*xx-yy);
  bf[10] =  2.890611442640554f*xy*z;
  bf[11] = -0.4570457994644658f*y*(4.0f*zz-xx-yy);
  bf[12] =  0.3731763325901154f*z*(2.0f*zz-3.0f*xx-3.0f*yy);
  bf[13] = -0.4570457994644658f*x*(4.0f*zz-xx-yy);
  bf[14] =  1.445305721320277f*z*(xx-yy);
  bf[15] = -0.5900435899266435f*x*(xx-yy-3.0f*zz);
  const float* S = sh + (long)shidx[i]*48;
  float cr=0.f, cg=0.f, cbl=0.f;
  #pragma unroll
  for (int j=0;j<16;j++) {
    float w = bf[j];
    cr  += w*S[j*3+0];
    cg  += w*S[j*3+1];
    cbl += w*S[j*3+2];
  }
  cr  = fmaxf(cr +0.5f, 0.0f);
  cg  = fmaxf(cg +0.5f, 0.0f);
  cbl = fmaxf(cbl+0.5f, 0.0f);

  ws[i]        = make_float4(gx, gy, rc, infront ? tz : __builtin_inff());
  ws[NG + i]   = make_float4(ca, cb, cc, op);
  ws[2*NG + i] = make_float4(cr, cg, cbl, 0.0f);
}

// tile_k: one block per 8x8 tile, 512 threads.
// A: stream c4, circle-box cull, LDS-compact keys (depth<<32|g : unique, stable).
// B: rank-count sort (2 barriers). C: gather sorted params to LDS.
// D: 8-way segment-split front-to-back blend + monoid combine.
__global__ __launch_bounds__(512) void tile_k(const float4* __restrict__ ws,
                                              const float* __restrict__ bg,
                                              float* __restrict__ out)
{
  __shared__ unsigned long long kds[CAP];
  __shared__ int   sidx[CAP];
  __shared__ float2 sgxy[CAP];
  __shared__ float4 sabc[CAP];
  __shared__ float4 scol[CAP];
  __shared__ float pT[8][64], pR[8][64], pG[8][64], pB[8][64];
  __shared__ int scnt;
  int tid = threadIdx.x;
  if (tid == 0) scnt = 0;
  __syncthreads();

  int tile = blockIdx.x;
  int x0 = (tile % 10) * 8, y0 = (tile / 10) * 8;
  float bx0 = (float)x0, bx1 = (float)(x0+7);
  float by0 = (float)y0, by1 = (float)(y0+7);

  for (int c = 0; c < NG/512; ++c) {
    int g = c*512 + tid;
    float4 v = ws[g];                      // gx, gy, rc, depth
    float nx = fminf(fmaxf(v.x, bx0), bx1) - v.x;
    float ny = fminf(fmaxf(v.y, by0), by1) - v.y;
    if (v.z > 0.0f && nx*nx + ny*ny <= v.z*v.z) {
      int slot = atomicAdd(&scnt, 1);
      if (slot < CAP)
        kds[slot] = ((unsigned long long)__float_as_uint(v.w) << 32) | (unsigned)g;
    }
  }
  __syncthreads();
  int cnt = scnt; if (cnt > CAP) cnt = CAP;

  // rank-count sort: keys unique (g in low bits), broadcast LDS reads
  for (int i = tid; i < cnt; i += 512) {
    unsigned long long ki = kds[i];
    int r = 0;
    for (int j = 0; j < cnt; ++j) r += (kds[j] < ki);
    sidx[r] = (int)(ki & 0xFFFFFFFFull);
  }
  __syncthreads();

  // gather params in sorted order
  for (int i = tid; i < cnt; i += 512) {
    int g = sidx[i];
    float4 v = ws[g];
    sgxy[i] = make_float2(v.x, v.y);
    sabc[i] = ws[NG + g];
    scol[i] = ws[2*NG + g];
  }
  __syncthreads();

  // blend: 8 segments x 64 lanes(=pixels)
  int wv = tid >> 6, lane = tid & 63;
  float px = (float)(x0 + (lane & 7));
  float py = (float)(y0 + (lane >> 3));
  int seg = (cnt + 7) >> 3;
  int s0i = wv*seg;
  int s1i = s0i + seg; if (s1i > cnt) s1i = cnt;
  float T = 1.0f, ar = 0.f, ag = 0.f, ab = 0.f;
  for (int e = s0i; e < s1i; ++e) {
    float2 xyv = sgxy[e];
    float4 q   = sabc[e];
    float dx = xyv.x - px, dy = xyv.y - py;
    float power = -0.5f*(q.x*dx*dx + q.z*dy*dy) - q.y*dx*dy;
    float al = 0.0f;
    if (power <= 0.0f) {
      float av = fminf(0.99f, q.w*__expf(power));
      if (av >= (1.0f/255.0f)) al = av;
    }
    float4 cl = scol[e];
    float w = al*T;
    ar += w*cl.x; ag += w*cl.y; ab += w*cl.z;
    T *= 1.0f - al;
    if (__ballot(T >= 1e-4f) == 0ull) break;  // own-partial >= global T; exact under ref cutoff
  }
  pT[wv][lane]=T; pR[wv][lane]=ar; pG[wv][lane]=ag; pB[wv][lane]=ab;
  __syncthreads();

  if (tid < 64) {
    float Tg = 1.0f, r = 0.f, g2 = 0.f, b2 = 0.f;
    #pragma unroll
    for (int w = 0; w < 8; ++w) {
      r  += Tg*pR[w][tid];
      g2 += Tg*pG[w][tid];
      b2 += Tg*pB[w][tid];
      Tg *= pT[w][tid];
    }
    int p = (y0 + (tid>>3))*WI + (x0 + (tid&7));
    out[0*NPIX+p] = r  + Tg*bg[0];
    out[1*NPIX+p] = g2 + Tg*bg[1];
    out[2*NPIX+p] = b2 + Tg*bg[2];
  }
}

extern "C" void kernel_launch(void* const* d_in, const int* in_sizes, int n_in,
                              void* d_out, int out_size, void* d_ws, size_t ws_size,
                              hipStream_t stream) {
  const float* means  = (const float*)d_in[0];
  const float* sh     = (const float*)d_in[1];
  const int*   shidx  = (const int*)  d_in[2];
  const int*   gidx   = (const int*)  d_in[3];
  const float* opac   = (const float*)d_in[4];
  const float* scales = (const float*)d_in[5];
  const float* sfac   = (const float*)d_in[6];
  const float* rots   = (const float*)d_in[7];
  const float* ext    = (const float*)d_in[8];
  const float* bg     = (const float*)d_in[9];
  float* out = (float*)d_out;
  float4* ws = (float4*)d_ws;

  prep_k<<<NG/256, 256, 0, stream>>>(means, sh, shidx, gidx, opac, scales, sfac,
                                     rots, ext, ws, out + 3*NPIX);
  tile_k<<<100, 512, 0, stream>>>(ws, bg, out);
}

// Round 5
// 93.862 us; speedup vs baseline: 2.0113x; 1.0403x over previous
//
#include <hip/hip_runtime.h>
#include <math.h>

#define NG 4096
#define WI 80
#define HI 80
#define NPIX (WI*HI)
#define FOCAL 40.0f
#define LIM 1.3f
#define CAP 1024

#define SH_C0 0.28209479177387814f
#define SH_C1 0.4886025119029199f

// ws layout (float4 slots):
//   c4[i]   = {gx, gy, rcx, rcy}     (per-axis exact cull extents)
//   a4[i]   = {ca, cb, cc, op}
//   col4[i] = {r, g, b, depth}
__global__ __launch_bounds__(256) void prep_k(
    const float* __restrict__ means, const float* __restrict__ sh,
    const int* __restrict__ shidx, const int* __restrict__ gidx,
    const float* __restrict__ opac, const float* __restrict__ scales,
    const float* __restrict__ sfac, const float* __restrict__ rots,
    const float* __restrict__ ext, float4* __restrict__ ws,
    float* __restrict__ radii_out)
{
  int i = blockIdx.x*blockDim.x + threadIdx.x;
  if (i >= NG) return;
  float e0=ext[0],  e1=ext[1],  e2=ext[2];
  float e4=ext[4],  e5=ext[5],  e6=ext[6];
  float e8=ext[8],  e9=ext[9],  e10=ext[10];
  float e12=ext[12], e13=ext[13], e14=ext[14];
  float m0=means[3*i+0], m1=means[3*i+1], m2=means[3*i+2];
  float tx = m0*e0 + m1*e4 + m2*e8  + e12;
  float ty = m0*e1 + m1*e5 + m2*e9  + e13;
  float tz = m0*e2 + m1*e6 + m2*e10 + e14;
  bool infront = tz > 0.2f;
  float tzs = infront ? tz : 1.0f;
  float inv_tzs = 1.0f / tzs;
  float gx = ((tx*inv_tzs + 1.0f)*WI - 1.0f)*0.5f;
  float gy = ((ty*inv_tzs + 1.0f)*HI - 1.0f)*0.5f;

  int gi = gidx[i];
  float sf = sfac[i];
  float s0 = scales[3*gi+0]*sf, s1 = scales[3*gi+1]*sf, s2 = scales[3*gi+2]*sf;
  float qw = rots[4*gi+0], qx = rots[4*gi+1], qy = rots[4*gi+2], qz = rots[4*gi+3];
  float qinv = rsqrtf(qw*qw+qx*qx+qy*qy+qz*qz);
  qw*=qinv; qx*=qinv; qy*=qinv; qz*=qinv;
  float r00 = 1.0f - 2.0f*(qy*qy+qz*qz);
  float r01 = 2.0f*(qx*qy - qw*qz);
  float r02 = 2.0f*(qx*qz + qw*qy);
  float r10 = 2.0f*(qx*qy + qw*qz);
  float r11 = 1.0f - 2.0f*(qx*qx+qz*qz);
  float r12 = 2.0f*(qy*qz - qw*qx);
  float r20 = 2.0f*(qx*qz - qw*qy);
  float r21 = 2.0f*(qy*qz + qw*qx);
  float r22 = 1.0f - 2.0f*(qx*qx+qy*qy);
  float v0 = s0*s0, v1 = s1*s1, v2 = s2*s2;
  float C00 = r00*r00*v0 + r01*r01*v1 + r02*r02*v2;
  float C01 = r00*r10*v0 + r01*r11*v1 + r02*r12*v2;
  float C02 = r00*r20*v0 + r01*r21*v1 + r02*r22*v2;
  float C11 = r10*r10*v0 + r11*r11*v1 + r12*r12*v2;
  float C12 = r10*r20*v0 + r11*r21*v1 + r12*r22*v2;
  float C22 = r20*r20*v0 + r21*r21*v1 + r22*r22*v2;
  float W0x=e0, W0y=e4, W0z=e8;
  float W1x=e1, W1y=e5, W1z=e9;
  float W2x=e2, W2y=e6, W2z=e10;
  float B00 = W0x*C00 + W0y*C01 + W0z*C02;
  float B01 = W0x*C01 + W0y*C11 + W0z*C12;
  float B02 = W0x*C02 + W0y*C12 + W0z*C22;
  float B10 = W1x*C00 + W1y*C01 + W1z*C02;
  float B11 = W1x*C01 + W1y*C11 + W1z*C12;
  float B12 = W1x*C02 + W1y*C12 + W1z*C22;
  float B20 = W2x*C00 + W2y*C01 + W2z*C02;
  float B21 = W2x*C01 + W2y*C11 + W2z*C12;
  float B22 = W2x*C02 + W2y*C12 + W2z*C22;
  float V00 = B00*W0x + B01*W0y + B02*W0z;
  float V01 = B00*W1x + B01*W1y + B02*W1z;
  float V02 = B00*W2x + B01*W2y + B02*W2z;
  float V11 = B10*W1x + B11*W1y + B12*W1z;
  float V12 = B10*W2x + B11*W2y + B12*W2z;
  float V22 = B20*W2x + B21*W2y + B22*W2z;
  float txz = tx*inv_tzs, tyz = ty*inv_tzs;
  float txc = fminf(fmaxf(txz, -LIM), LIM) * tzs;
  float tyc = fminf(fmaxf(tyz, -LIM), LIM) * tzs;
  float jx  = FOCAL*inv_tzs;
  float jy  = FOCAL*inv_tzs;
  float jz0 = -FOCAL*txc*inv_tzs*inv_tzs;
  float jz1 = -FOCAL*tyc*inv_tzs*inv_tzs;
  float c00 = jx*jx*V00 + 2.0f*jx*jz0*V02 + jz0*jz0*V22;
  float c01 = jx*jy*V01 + jx*jz1*V02 + jz0*jy*V12 + jz0*jz1*V22;
  float c11 = jy*jy*V11 + 2.0f*jy*jz1*V12 + jz1*jz1*V22;
  float a = c00 + 0.3f;
  float b = c01;
  float cf = c11 + 0.3f;
  float det = a*cf - b*b;
  bool valid = infront && (det > 0.0f);
  float dets = (det != 0.0f) ? det : 1.0f;
  float ca = cf/dets, cb = -b/dets, cc = a/dets;
  float mid = 0.5f*(a+cf);
  float lam1 = mid + sqrtf(fmaxf(0.1f, mid*mid - det));
  float radf = valid ? ceilf(3.0f*sqrtf(lam1)) : 0.0f;
  radii_out[i] = radf;

  float op = valid ? opac[i] : 0.0f;
  // Exact per-axis extents of the {alpha >= 1/255} ellipse:
  // d^T conic d <= 2L (L = ln(255 op)) has bbox half-widths sqrt(2L*a), sqrt(2L*c)
  // (a,c = cov2d diagonal = conic^{-1} diagonal). Superset of ref's kept set -> exact.
  float L2 = 2.0f*fmaxf(0.0f, logf(255.0f*op));
  float rcx = valid ? sqrtf(L2*a)  + 0.01f : 0.0f;
  float rcy = valid ? sqrtf(L2*cf) + 0.01f : 0.0f;

  float cp0 = -(e12*e0 + e13*e1 + e14*e2);
  float cp1 = -(e12*e4 + e13*e5 + e14*e6);
  float cp2 = -(e12*e8 + e13*e9 + e14*e10);
  float dx0 = m0-cp0, dy0 = m1-cp1, dz0 = m2-cp2;
  float dn = rsqrtf(dx0*dx0+dy0*dy0+dz0*dz0);
  float x = dx0*dn, y = dy0*dn, z = dz0*dn;
  float xx=x*x, yy=y*y, zz=z*z;
  float xy=x*y, yz=y*z, xz=x*z;
  float bf[16];
  bf[0]  = SH_C0;
  bf[1]  = -SH_C1*y;
  bf[2]  =  SH_C1*z;
  bf[3]  = -SH_C1*x;
  bf[4]  =  1.0925484305920792f*xy;
  bf[5]  = -1.0925484305920792f*yz;
  bf[6]  =  0.31539156525252005f*(2.0f*zz-xx-yy);
  bf[7]  = -1.0925484305920792f*xz;
  bf[8]  =  0.5462742152960396f*(xx-yy);
  bf[9]  = -0.5900435899266435f*y*(3.0f*xx-yy);
  bf[10] =  2.890611442640554f*xy*z;
  bf[11] = -0.4570457994644658f*y*(4.0f*zz-xx-yy);
  bf[12] =  0.3731763325901154f*z*(2.0f*zz-3.0f*xx-3.0f*yy);
  bf[13] = -0.4570457994644658f*x*(4.0f*zz-xx-yy);
  bf[14] =  1.445305721320277f*z*(xx-yy);
  bf[15] = -0.5900435899266435f*x*(xx-yy-3.0f*zz);
  const float* S = sh + (long)shidx[i]*48;
  float cr=0.f, cg=0.f, cbl=0.f;
  #pragma unroll
  for (int j=0;j<16;j++) {
    float w = bf[j];
    cr  += w*S[j*3+0];
    cg  += w*S[j*3+1];
    cbl += w*S[j*3+2];
  }
  cr  = fmaxf(cr +0.5f, 0.0f);
  cg  = fmaxf(cg +0.5f, 0.0f);
  cbl = fmaxf(cbl+0.5f, 0.0f);

  ws[i]        = make_float4(gx, gy, rcx, rcy);
  ws[NG + i]   = make_float4(ca, cb, cc, op);
  ws[2*NG + i] = make_float4(cr, cg, cbl, infront ? tz : __builtin_inff());
}

// tile_k: one block per 8x8 tile, 512 threads (8 waves).
// A: stream c4, per-axis bbox cull, BALLOT-compact (1 atomic/wave/chunk).
// B: rank-count sort, inner loop unrolled x8 (batched LDS reads).
// C: gather sorted params. D: 8-way segment blend, unrolled x4, chunked early-out.
__global__ __launch_bounds__(512) void tile_k(const float4* __restrict__ ws,
                                              const float* __restrict__ bg,
                                              float* __restrict__ out)
{
  __shared__ unsigned long long kds[CAP];
  __shared__ int    sidx[CAP];
  __shared__ float2 sgxy[CAP];
  __shared__ float4 sabc[CAP];
  __shared__ float4 scol[CAP];
  __shared__ float pT[8][64], pR[8][64], pG[8][64], pB[8][64];
  __shared__ int scnt;
  int tid = threadIdx.x;
  int wv = tid >> 6, lane = tid & 63;
  if (tid == 0) scnt = 0;
  __syncthreads();

  int tile = blockIdx.x;
  int x0 = (tile % 10) * 8, y0 = (tile / 10) * 8;
  float bx0 = (float)x0, bx1 = (float)(x0+7);
  float by0 = (float)y0, by1 = (float)(y0+7);

  const float* wsf = (const float*)ws;
  for (int c = 0; c < NG/512; ++c) {
    int g = c*512 + tid;
    float4 v = ws[g];                       // gx, gy, rcx, rcy
    bool hit = (v.z > 0.0f) &&
               (v.x + v.z >= bx0) && (v.x - v.z <= bx1) &&
               (v.y + v.w >= by0) && (v.y - v.w <= by1);
    unsigned long long m = __ballot(hit);
    if (m) {
      int wcnt = __popcll(m);
      int base = 0;
      if (lane == 0) base = atomicAdd(&scnt, wcnt);
      base = __shfl(base, 0, 64);
      if (hit) {
        int pos = base + __popcll(m & ((1ull<<lane)-1ull));
        if (pos < CAP) {
          float depth = wsf[(2*NG + g)*4 + 3];
          kds[pos] = ((unsigned long long)__float_as_uint(depth) << 32) | (unsigned)g;
        }
      }
    }
  }
  __syncthreads();
  int cnt = scnt; if (cnt > CAP) cnt = CAP;

  // rank-count sort: keys unique (g in low bits); unroll batches LDS reads
  for (int i = tid; i < cnt; i += 512) {
    unsigned long long ki = kds[i];
    int r = 0;
    #pragma unroll 8
    for (int j = 0; j < cnt; ++j) r += (kds[j] < ki);
    sidx[r] = (int)(ki & 0xFFFFFFFFull);
  }
  __syncthreads();

  // gather params in sorted order
  for (int i = tid; i < cnt; i += 512) {
    int g = sidx[i];
    float4 v = ws[g];
    sgxy[i] = make_float2(v.x, v.y);
    sabc[i] = ws[NG + g];
    scol[i] = ws[2*NG + g];
  }
  __syncthreads();

  // blend: 8 segments x 64 lanes(=pixels)
  float px = (float)(x0 + (lane & 7));
  float py = (float)(y0 + (lane >> 3));
  int seg = (cnt + 7) >> 3;
  int s0i = wv*seg;
  int s1i = s0i + seg; if (s1i > cnt) s1i = cnt;
  float T = 1.0f, ar = 0.f, ag = 0.f, ab = 0.f;
  for (int e0 = s0i; e0 < s1i && __ballot(T >= 1e-4f); e0 += 16) {
    int e1 = e0 + 16; if (e1 > s1i) e1 = s1i;
    #pragma unroll 4
    for (int e = e0; e < e1; ++e) {
      float2 xyv = sgxy[e];
      float4 q   = sabc[e];
      float dx = xyv.x - px, dy = xyv.y - py;
      float power = -0.5f*(q.x*dx*dx + q.z*dy*dy) - q.y*dx*dy;
      float al = 0.0f;
      if (power <= 0.0f) {
        float av = fminf(0.99f, q.w*__expf(power));
        if (av >= (1.0f/255.0f)) al = av;
      }
      float4 cl = scol[e];
      float w = al*T;
      ar += w*cl.x; ag += w*cl.y; ab += w*cl.z;
      T *= 1.0f - al;
    }
  }
  pT[wv][lane]=T; pR[wv][lane]=ar; pG[wv][lane]=ag; pB[wv][lane]=ab;
  __syncthreads();

  if (tid < 64) {
    float Tg = 1.0f, r = 0.f, g2 = 0.f, b2 = 0.f;
    #pragma unroll
    for (int w = 0; w < 8; ++w) {
      r  += Tg*pR[w][tid];
      g2 += Tg*pG[w][tid];
      b2 += Tg*pB[w][tid];
      Tg *= pT[w][tid];
    }
    int p = (y0 + (tid>>3))*WI + (x0 + (tid&7));
    out[0*NPIX+p] = r  + Tg*bg[0];
    out[1*NPIX+p] = g2 + Tg*bg[1];
    out[2*NPIX+p] = b2 + Tg*bg[2];
  }
}

extern "C" void kernel_launch(void* const* d_in, const int* in_sizes, int n_in,
                              void* d_out, int out_size, void* d_ws, size_t ws_size,
                              hipStream_t stream) {
  const float* means  = (const float*)d_in[0];
  const float* sh     = (const float*)d_in[1];
  const int*   shidx  = (const int*)  d_in[2];
  const int*   gidx   = (const int*)  d_in[3];
  const float* opac   = (const float*)d_in[4];
  const float* scales = (const float*)d_in[5];
  const float* sfac   = (const float*)d_in[6];
  const float* rots   = (const float*)d_in[7];
  const float* ext    = (const float*)d_in[8];
  const float* bg     = (const float*)d_in[9];
  float* out = (float*)d_out;
  float4* ws = (float4*)d_ws;

  prep_k<<<NG/256, 256, 0, stream>>>(means, sh, shidx, gidx, opac, scales, sfac,
                                     rots, ext, ws, out + 3*NPIX);
  tile_k<<<100, 512, 0, stream>>>(ws, bg, out);
}